// Round 17
// baseline (365.033 us; speedup 1.0000x reference)
//
#include <hip/hip_runtime.h>
#include <hip/hip_bf16.h>

// GAT layer for MI355X (gfx950). FP32 in/out.
// R16 post-mortem: wh blocks placed LAST ran serially after pack (pack's 2048
// blocks fill all CU slots instantly). R17: (1) wh blocks FIRST -> true
// overlap under the adj stream; (2) reduce dispatch replaced by deterministic
// ticket-ordered split-k accumulation inside flash (ks-major block index ->
// same-rb chain on one XCD; acquire/release + threadfence; fixed ks order =
// bit-deterministic; turn[] re-zeroed by wh block 0 every call).
// Pipeline (2 dispatches): whpack -> flash6t.

typedef __bf16 bf16;
typedef __attribute__((ext_vector_type(8))) __bf16 bf16x8;
typedef __attribute__((ext_vector_type(4))) float f32x4;

#define NN 8192
#define F_IN 256
#define F_OUT 128
#define LOG2E 1.44269504088896f
#define ALPHA 0.2f

__device__ __forceinline__ void split8(const float* __restrict__ p,
                                       bf16x8& hi, bf16x8& lo) {
    const float4 u = *(const float4*)p;
    const float4 v = *(const float4*)(p + 4);
    float f[8] = {u.x, u.y, u.z, u.w, v.x, v.y, v.z, v.w};
#pragma unroll
    for (int j = 0; j < 8; ++j) {
        const bf16 h = (bf16)f[j];
        hi[j] = h;
        lo[j] = (bf16)(f[j] - (float)h);
    }
}

// ---------------------------------------------------------------------------
// K1: whpack — blocks 0..127: Wh GEMM (+f12) — FIRST so they get CU slots
// at t=0 and overlap the pack stream. Block 0 also zeroes turn[64].
// Blocks 128..2175: pack adj -> bitmask (R12's lane-contiguous packer).
// ---------------------------------------------------------------------------
__global__ __launch_bounds__(256) void gat_whpack(
        const int* __restrict__ adj,
        const float* __restrict__ h,
        const float* __restrict__ W,
        const float* __restrict__ a,
        unsigned char* __restrict__ maskP,
        bf16* __restrict__ WhT,
        float* __restrict__ f1L,
        float* __restrict__ f2L,
        int* __restrict__ turn) {
    const int tid = threadIdx.x;

    if (blockIdx.x >= 128) {
        // ---------------- pack ----------------
        const int row = (blockIdx.x - 128) * 4 + (tid >> 6);
        const int l = tid & 63;
        const int* rowp = adj + (size_t)row * NN;

#pragma unroll 4
        for (int iter = 0; iter < 16; ++iter) {
            const int base = iter * 512;
            const int4 v1 = *(const int4*)(rowp + base + l * 4);
            const int4 v2 = *(const int4*)(rowp + base + 256 + l * 4);
            unsigned int n1 = (v1.x > 0 ? 1u : 0u) | (v1.y > 0 ? 2u : 0u) |
                              (v1.z > 0 ? 4u : 0u) | (v1.w > 0 ? 8u : 0u);
            unsigned int n2 = (v2.x > 0 ? 1u : 0u) | (v2.y > 0 ? 2u : 0u) |
                              (v2.z > 0 ? 4u : 0u) | (v2.w > 0 ? 8u : 0u);
            const unsigned int p1 = __shfl_xor(n1, 1);
            const unsigned int p2 = __shfl_xor(n2, 1);
            if ((l & 1) == 0) {
                const int b1 = iter * 64 + (l >> 1);  // byte index 0..1023
                const int b2 = b1 + 32;
                maskP[((size_t)(b1 >> 7) << 20) + (size_t)row * 128 + (b1 & 127)] =
                    (unsigned char)(n1 | (p1 << 4));
                maskP[((size_t)(b2 >> 7) << 20) + (size_t)row * 128 + (b2 & 127)] =
                    (unsigned char)(n2 | (p2 << 4));
            }
        }
        return;
    }

    // ---------------- wh (+f12) ----------------
    if (blockIdx.x == 0 && tid < 64) turn[tid] = 0;  // ticket init, every call

    const int wb = blockIdx.x;  // 0..127
    const int wv = tid >> 6;
    const int l15 = tid & 15;
    const int g = (tid & 63) >> 4;
    const int rowbase = wb * 64 + wv * 16;

    f32x4 acc[8];
    const f32x4 zz = {0.f, 0.f, 0.f, 0.f};
#pragma unroll
    for (int nf = 0; nf < 8; ++nf) acc[nf] = zz;

#pragma unroll
    for (int ks = 0; ks < 8; ++ks) {
        const int k = ks * 32 + g * 8;
        bf16x8 ah, al;
        split8(h + (size_t)(rowbase + l15) * F_IN + k, ah, al);
#pragma unroll
        for (int nf = 0; nf < 8; ++nf) {
            bf16x8 bh, bl;
            split8(W + (size_t)(nf * 16 + l15) * F_IN + k, bh, bl);
            acc[nf] = __builtin_amdgcn_mfma_f32_16x16x32_bf16(ah, bh, acc[nf], 0, 0, 0);
            acc[nf] = __builtin_amdgcn_mfma_f32_16x16x32_bf16(ah, bl, acc[nf], 0, 0, 0);
            acc[nf] = __builtin_amdgcn_mfma_f32_16x16x32_bf16(al, bh, acc[nf], 0, 0, 0);
        }
    }

#pragma unroll
    for (int nf = 0; nf < 8; ++nf)
#pragma unroll
        for (int r = 0; r < 4; ++r)
            WhT[(size_t)(nf * 16 + l15) * NN + rowbase + g * 4 + r] = (bf16)acc[nf][r];

    float a1c[8], a2c[8];
#pragma unroll
    for (int nf = 0; nf < 8; ++nf) {
        a1c[nf] = a[nf * 16 + l15];
        a2c[nf] = a[F_OUT + nf * 16 + l15];
    }
#pragma unroll
    for (int r = 0; r < 4; ++r) {
        float s1 = 0.f, s2 = 0.f;
#pragma unroll
        for (int nf = 0; nf < 8; ++nf) {
            s1 += acc[nf][r] * a1c[nf];
            s2 += acc[nf][r] * a2c[nf];
        }
        s1 += __shfl_xor(s1, 1, 16);
        s1 += __shfl_xor(s1, 2, 16);
        s1 += __shfl_xor(s1, 4, 16);
        s1 += __shfl_xor(s1, 8, 16);
        s2 += __shfl_xor(s2, 1, 16);
        s2 += __shfl_xor(s2, 2, 16);
        s2 += __shfl_xor(s2, 4, 16);
        s2 += __shfl_xor(s2, 8, 16);
        if (l15 == 0) {
            f1L[rowbase + g * 4 + r] = s1 * LOG2E;
            f2L[rowbase + g * 4 + r] = s2 * LOG2E;
        }
    }
}

// ---------------------------------------------------------------------------
// K2: flash6t — R12's flash6 compute core + ticket-ordered split-k epilogue.
// Grid 512, ks-major: ks = bx>>6, rb = bx&63 (same-rb chain lands on one XCD).
// Compute: 8 chunks of k=128 (stage B 32KB + mask 2KB; 4 MFMA steps each).
// Epilogue: spin on turn[rb]==ks (acquire+inv), accumulate accL into
// O_acc[rb] (ks==0 writes, 1..6 RMW, 7 RMW+divide+store out), release.
// ---------------------------------------------------------------------------
#define RSOFF 34048  // accL[64][132] f32 ends at 33792; rsL/rsF above it

__global__ __launch_bounds__(512, 4) void gat_flash6t(
        const unsigned char* __restrict__ maskP,
        const bf16* __restrict__ WhT,
        const float* __restrict__ f1L,
        const float* __restrict__ f2L,
        float* __restrict__ rs_part,
        float* __restrict__ O_acc,
        int* __restrict__ turn,
        float* __restrict__ out) {
    __shared__ __align__(16) char lds[39424];
    // [0,32768): B chunk [128c][128k] swizzled
    // [32768,35328): mask chunk [128 rows][20B padded]
    // [35328,39424): f2 slice (1024 f32)
    // epilogue reuse: accL[64][132] at 0; rsL at RSOFF; rsF at RSOFF+512

    const int tid = threadIdx.x;
    const int wv = tid >> 6;
    const int l = tid & 63;
    const int l15 = l & 15;
    const int g = l >> 4;
    const int ks = blockIdx.x >> 6;  // 0..7 (k-slice)
    const int rb = blockIdx.x & 63;  // 0..63 (row tile)
    const int row0 = rb * 128;
    const int lrow = wv * 16 + l15;

    const float f1a = f1L[row0 + lrow];

    const int mr = tid >> 2;
    const int mseg = tid & 3;
    const unsigned char* msrc =
        maskP + ((size_t)ks << 20) + (size_t)(row0 + mr) * 128 + mseg * 4;

    f32x4 acc[8];
    const f32x4 zz = {0.f, 0.f, 0.f, 0.f};
#pragma unroll
    for (int nf = 0; nf < 8; ++nf) acc[nf] = zz;
    float rs0 = 0.f;

    // f2 slice -> LDS
    {
        const float2 v = *(const float2*)(f2L + ks * 1024 + tid * 2);
        *(float2*)(lds + 35328 + tid * 8) = v;
    }

    for (int it = 0; it < 8; ++it) {
        __syncthreads();
        const unsigned int mw = *(const unsigned int*)(msrc + it * 16);
        *(unsigned int*)(lds + 32768 + mr * 20 + mseg * 4) = mw;
#pragma unroll
        for (int j = 0; j < 4; ++j) {
            const int u = j * 512 + tid;
            const int cc = u >> 4;
            const int ku = u & 15;
            const bf16x8 v =
                *(const bf16x8*)(WhT + (size_t)cc * NN + ks * 1024 + it * 128 + ku * 8);
            *(bf16x8*)(lds + ((cc * 256 + ku * 16) ^ ((cc & 7) << 4))) = v;
        }
        __syncthreads();

#pragma unroll
        for (int s = 0; s < 4; ++s) {
            const unsigned int mb =
                *(const unsigned char*)(lds + 32768 + lrow * 20 + s * 4 + g);
            const int t = it * 4 + s;
            const float4 fa = *(const float4*)(lds + 35328 + t * 128 + g * 32);
            const float4 fb = *(const float4*)(lds + 35328 + t * 128 + g * 32 + 16);
            const float ff[8] = {fa.x, fa.y, fa.z, fa.w, fb.x, fb.y, fb.z, fb.w};

            bf16x8 pa;
#pragma unroll
            for (int j = 0; j < 8; ++j) {
                const float x = f1a + ff[j];
                const float e = __builtin_amdgcn_exp2f(fmaxf(x, ALPHA * x));
                pa[j] = (bf16)((mb & (1u << j)) ? e : 0.f);
            }
#pragma unroll
            for (int j = 0; j < 8; ++j) rs0 += (float)pa[j];

            __builtin_amdgcn_s_setprio(1);
#pragma unroll
            for (int nf = 0; nf < 8; ++nf) {
                const int c = nf * 16 + l15;
                const bf16x8 bh = *(const bf16x8*)(
                    lds + ((c * 256 + s * 64 + g * 16) ^ ((c & 7) << 4)));
                acc[nf] = __builtin_amdgcn_mfma_f32_16x16x32_bf16(pa, bh, acc[nf], 0, 0, 0);
            }
            __builtin_amdgcn_s_setprio(0);
        }
    }

    // rowsum partial
    rs0 += __shfl_xor(rs0, 16);
    rs0 += __shfl_xor(rs0, 32);
    if (l < 16) {
        if (ks < 7)
            rs_part[(size_t)ks * NN + row0 + lrow] = rs0;  // plain store, pre-release
        else
            *(float*)(lds + RSOFF + lrow * 4) = rs0;  // own partial, via LDS
    }
    __syncthreads();

    // ---- ticket: wait for predecessor slice (deterministic ks order) ----
    if (tid == 0 && ks > 0) {
        while (__hip_atomic_load(&turn[rb], __ATOMIC_ACQUIRE,
                                 __HIP_MEMORY_SCOPE_AGENT) < ks)
            __builtin_amdgcn_s_sleep(8);
        __threadfence();  // invalidate stale O_acc/rs_part in this XCD's caches
    }
    __syncthreads();

    // ks==7: total rowsums -> rsF (needs predecessors' rs_part, now visible)
    if (ks == 7 && tid < 128) {
        float r = *(const float*)(lds + RSOFF + tid * 4);
#pragma unroll
        for (int s = 0; s < 7; ++s) r += rs_part[(size_t)s * NN + row0 + tid];
        *(float*)(lds + RSOFF + 512 + tid * 4) = 1.0f / r;
    }

    float* accL = (float*)lds;
    float* O_blk = O_acc + (size_t)rb * (128 * 128);

#pragma unroll
    for (int hh = 0; hh < 2; ++hh) {
        __syncthreads();
        if ((wv >> 2) == hh) {
            const int rbase = (wv & 3) * 16;
#pragma unroll
            for (int nf = 0; nf < 8; ++nf)
#pragma unroll
                for (int r = 0; r < 4; ++r)
                    accL[(rbase + g * 4 + r) * 132 + nf * 16 + l15] = acc[nf][r];
        }
        __syncthreads();
        const int rr = tid >> 3;  // 0..63
        const int seg = tid & 7;  // 16 floats
        const float* src = accL + rr * 132 + seg * 16;
        const int grow = hh * 64 + rr;
        if (ks == 0) {
            float* dst = O_blk + (size_t)grow * 128 + seg * 16;
#pragma unroll
            for (int j = 0; j < 4; ++j)
                *(float4*)(dst + j * 4) = *(const float4*)(src + j * 4);
        } else if (ks < 7) {
            float* dst = O_blk + (size_t)grow * 128 + seg * 16;
#pragma unroll
            for (int j = 0; j < 4; ++j) {
                float4 v = *(const float4*)(dst + j * 4);
                const float4 u = *(const float4*)(src + j * 4);
                v.x += u.x; v.y += u.y; v.z += u.z; v.w += u.w;
                *(float4*)(dst + j * 4) = v;
            }
        } else {
            const float inv = *(const float*)(lds + RSOFF + 512 + grow * 4);
            const float* osrc = O_blk + (size_t)grow * 128 + seg * 16;
            float* dst = out + (size_t)(row0 + grow) * F_OUT + seg * 16;
#pragma unroll
            for (int j = 0; j < 4; ++j) {
                float4 v = *(const float4*)(osrc + j * 4);
                const float4 u = *(const float4*)(src + j * 4);
                v.x = (v.x + u.x) * inv; v.y = (v.y + u.y) * inv;
                v.z = (v.z + u.z) * inv; v.w = (v.w + u.w) * inv;
                *(float4*)(dst + j * 4) = v;
            }
        }
    }

    __syncthreads();
    if (tid == 0 && ks < 7) {
        __threadfence();  // flush O_acc/rs_part writes device-wide
        __hip_atomic_store(&turn[rb], ks + 1, __ATOMIC_RELEASE,
                           __HIP_MEMORY_SCOPE_AGENT);
    }
}

// ---------------------------------------------------------------------------
extern "C" void kernel_launch(void* const* d_in, const int* in_sizes, int n_in,
                              void* d_out, int out_size, void* d_ws, size_t ws_size,
                              hipStream_t stream) {
    const float* h = (const float*)d_in[0];  // (8192, 256) fp32
    const int* adj = (const int*)d_in[1];    // (8192, 8192) int32
    const float* W = (const float*)d_in[2];  // (128, 256) fp32
    const float* a = (const float*)d_in[3];  // (1, 256) fp32
    float* out = (float*)d_out;              // (8192, 128) fp32

    char* ws = (char*)d_ws;
    const size_t MB = 1024 * 1024;
    bf16* WhT = (bf16*)ws;                                 // 2 MB
    float* f1L = (float*)(ws + 2 * MB);                    // 32 KB
    float* f2L = f1L + NN;                                 // 32 KB
    int* turn = (int*)(ws + 2 * MB + 64 * 1024);           // 256 B
    unsigned char* maskP = (unsigned char*)(ws + 3 * MB);  // 8 MB [ks][row][128B]
    float* rs_part = (float*)(ws + 11 * MB);               // 256 KB (7 slices used)
    float* O_acc = (float*)(ws + 12 * MB);                 // 4 MB [64][128][128]

    gat_whpack<<<2176, 256, 0, stream>>>(adj, h, W, a, maskP, WhT, f1L, f2L, turn);
    gat_flash6t<<<512, 512, 0, stream>>>(maskP, WhT, f1L, f2L, rs_part, O_acc, turn, out);
}

// Round 19
// 105.724 us; speedup vs baseline: 3.4527x; 3.4527x over previous
//
#include <hip/hip_runtime.h>
#include <hip/hip_bf16.h>

// GAT layer for MI355X (gfx950). FP32 in/out.
// R17 post-mortem: ticket-ordered split-k serialized the whole grid (330 us).
// Reverted to the proven R12 split pipeline. Kept: wh blocks FIRST (R16
// placed them last -> serial). New: non-temporal adj loads in pack (single-
// use stream; don't evict WhT/mask from L2/L3). R18 fix: nontemporal builtin
// needs a clang ext_vector type, not HIP_vector_type -> i32x4.
// Pipeline (3 dispatches): whpack(wh first) -> flash6 -> reduce.

typedef __bf16 bf16;
typedef __attribute__((ext_vector_type(8))) __bf16 bf16x8;
typedef __attribute__((ext_vector_type(4))) float f32x4;
typedef __attribute__((ext_vector_type(4))) int i32x4;

#define NN 8192
#define F_IN 256
#define F_OUT 128
#define LOG2E 1.44269504088896f
#define ALPHA 0.2f
#define KSLICES 8

__device__ __forceinline__ void split8(const float* __restrict__ p,
                                       bf16x8& hi, bf16x8& lo) {
    const float4 u = *(const float4*)p;
    const float4 v = *(const float4*)(p + 4);
    float f[8] = {u.x, u.y, u.z, u.w, v.x, v.y, v.z, v.w};
#pragma unroll
    for (int j = 0; j < 8; ++j) {
        const bf16 h = (bf16)f[j];
        hi[j] = h;
        lo[j] = (bf16)(f[j] - (float)h);
    }
}

// ---------------------------------------------------------------------------
// K1: whpack — blocks 0..127: Wh GEMM (+f12) FIRST (get CU slots at t=0,
// overlap under the pack stream). Blocks 128..2175: pack adj -> bitmask
// (lane-contiguous 1KB/instruction reads, non-temporal).
// ---------------------------------------------------------------------------
__global__ __launch_bounds__(256) void gat_whpack(
        const int* __restrict__ adj,
        const float* __restrict__ h,
        const float* __restrict__ W,
        const float* __restrict__ a,
        unsigned char* __restrict__ maskP,
        bf16* __restrict__ WhT,
        float* __restrict__ f1L,
        float* __restrict__ f2L) {
    const int tid = threadIdx.x;

    if (blockIdx.x >= 128) {
        // ---------------- pack ----------------
        const int row = (blockIdx.x - 128) * 4 + (tid >> 6);
        const int l = tid & 63;
        const int* rowp = adj + (size_t)row * NN;

#pragma unroll 4
        for (int iter = 0; iter < 16; ++iter) {
            const int base = iter * 512;
            const i32x4 v1 =
                __builtin_nontemporal_load((const i32x4*)(rowp + base + l * 4));
            const i32x4 v2 =
                __builtin_nontemporal_load((const i32x4*)(rowp + base + 256 + l * 4));
            unsigned int n1 = (v1[0] > 0 ? 1u : 0u) | (v1[1] > 0 ? 2u : 0u) |
                              (v1[2] > 0 ? 4u : 0u) | (v1[3] > 0 ? 8u : 0u);
            unsigned int n2 = (v2[0] > 0 ? 1u : 0u) | (v2[1] > 0 ? 2u : 0u) |
                              (v2[2] > 0 ? 4u : 0u) | (v2[3] > 0 ? 8u : 0u);
            const unsigned int p1 = __shfl_xor(n1, 1);
            const unsigned int p2 = __shfl_xor(n2, 1);
            if ((l & 1) == 0) {
                const int b1 = iter * 64 + (l >> 1);  // byte index 0..1023
                const int b2 = b1 + 32;
                maskP[((size_t)(b1 >> 7) << 20) + (size_t)row * 128 + (b1 & 127)] =
                    (unsigned char)(n1 | (p1 << 4));
                maskP[((size_t)(b2 >> 7) << 20) + (size_t)row * 128 + (b2 & 127)] =
                    (unsigned char)(n2 | (p2 << 4));
            }
        }
        return;
    }

    // ---------------- wh (+f12) ----------------
    const int wb = blockIdx.x;  // 0..127
    const int wv = tid >> 6;
    const int l15 = tid & 15;
    const int g = (tid & 63) >> 4;
    const int rowbase = wb * 64 + wv * 16;

    f32x4 acc[8];
    const f32x4 zz = {0.f, 0.f, 0.f, 0.f};
#pragma unroll
    for (int nf = 0; nf < 8; ++nf) acc[nf] = zz;

#pragma unroll
    for (int ks = 0; ks < 8; ++ks) {
        const int k = ks * 32 + g * 8;
        bf16x8 ah, al;
        split8(h + (size_t)(rowbase + l15) * F_IN + k, ah, al);
#pragma unroll
        for (int nf = 0; nf < 8; ++nf) {
            bf16x8 bh, bl;
            split8(W + (size_t)(nf * 16 + l15) * F_IN + k, bh, bl);
            acc[nf] = __builtin_amdgcn_mfma_f32_16x16x32_bf16(ah, bh, acc[nf], 0, 0, 0);
            acc[nf] = __builtin_amdgcn_mfma_f32_16x16x32_bf16(ah, bl, acc[nf], 0, 0, 0);
            acc[nf] = __builtin_amdgcn_mfma_f32_16x16x32_bf16(al, bh, acc[nf], 0, 0, 0);
        }
    }

#pragma unroll
    for (int nf = 0; nf < 8; ++nf)
#pragma unroll
        for (int r = 0; r < 4; ++r)
            WhT[(size_t)(nf * 16 + l15) * NN + rowbase + g * 4 + r] = (bf16)acc[nf][r];

    float a1c[8], a2c[8];
#pragma unroll
    for (int nf = 0; nf < 8; ++nf) {
        a1c[nf] = a[nf * 16 + l15];
        a2c[nf] = a[F_OUT + nf * 16 + l15];
    }
#pragma unroll
    for (int r = 0; r < 4; ++r) {
        float s1 = 0.f, s2 = 0.f;
#pragma unroll
        for (int nf = 0; nf < 8; ++nf) {
            s1 += acc[nf][r] * a1c[nf];
            s2 += acc[nf][r] * a2c[nf];
        }
        s1 += __shfl_xor(s1, 1, 16);
        s1 += __shfl_xor(s1, 2, 16);
        s1 += __shfl_xor(s1, 4, 16);
        s1 += __shfl_xor(s1, 8, 16);
        s2 += __shfl_xor(s2, 1, 16);
        s2 += __shfl_xor(s2, 2, 16);
        s2 += __shfl_xor(s2, 4, 16);
        s2 += __shfl_xor(s2, 8, 16);
        if (l15 == 0) {
            f1L[rowbase + g * 4 + r] = s1 * LOG2E;
            f2L[rowbase + g * 4 + r] = s2 * LOG2E;
        }
    }
}

// ---------------------------------------------------------------------------
// K2: flash6 (verbatim R12). Grid 512 = 64 row-tiles(128 rows) x 8 k-slices
// (ks = bx&7 -> each XCD's blocks share one 256 KB B-slice + 1 MB mask slice
// in its L2). 512 thr, 8 waves; wave = 16 rows x 128 cols. 8 chunks of k=128:
//   [sync][stage B 32KB (lane-contiguous, swizzled LDS) + mask 2KB][sync]
//   [4 steps: mask byte + f2 from LDS -> 8 exp -> pa; 8 ds_read_b128 + MFMA]
// ---------------------------------------------------------------------------
__global__ __launch_bounds__(512, 4) void gat_flash6(
        const unsigned char* __restrict__ maskP,
        const bf16* __restrict__ WhT,
        const float* __restrict__ f1L,
        const float* __restrict__ f2L,
        float* __restrict__ O_part,
        float* __restrict__ rs_part) {
    __shared__ __align__(16) char lds[39424];
    // [0,32768): B chunk [128c][128k] swizzled
    // [32768,35328): mask chunk [128 rows][20B padded stride, 16B used]
    // [35328,39424): f2 slice (1024 f32)
    // epilogue reuse: accL[64][132] f32 at offset 0

    const int tid = threadIdx.x;
    const int wv = tid >> 6;
    const int l = tid & 63;
    const int l15 = l & 15;
    const int g = l >> 4;
    const int rb = blockIdx.x >> 3;
    const int ks = blockIdx.x & 7;
    const int row0 = rb * 128;
    const int lrow = wv * 16 + l15;

    const float f1a = f1L[row0 + lrow];

    const int mr = tid >> 2;   // mask staging row
    const int mseg = tid & 3;  // 4B segment
    const unsigned char* msrc =
        maskP + ((size_t)ks << 20) + (size_t)(row0 + mr) * 128 + mseg * 4;

    f32x4 acc[8];
    const f32x4 zz = {0.f, 0.f, 0.f, 0.f};
#pragma unroll
    for (int nf = 0; nf < 8; ++nf) acc[nf] = zz;
    float rs0 = 0.f;

    // f2 slice -> LDS (visible after the first stage barrier pair)
    {
        const float2 v = *(const float2*)(f2L + ks * 1024 + tid * 2);
        *(float2*)(lds + 35328 + tid * 8) = v;
    }

    for (int it = 0; it < 8; ++it) {
        __syncthreads();  // previous chunk fully consumed
        // ---- stage mask chunk (2KB) ----
        const unsigned int mw = *(const unsigned int*)(msrc + it * 16);
        *(unsigned int*)(lds + 32768 + mr * 20 + mseg * 4) = mw;
        // ---- stage B chunk (32KB), lane-contiguous reads, swizzled writes ----
#pragma unroll
        for (int j = 0; j < 4; ++j) {
            const int u = j * 512 + tid;
            const int cc = u >> 4;
            const int ku = u & 15;
            const bf16x8 v =
                *(const bf16x8*)(WhT + (size_t)cc * NN + ks * 1024 + it * 128 + ku * 8);
            *(bf16x8*)(lds + ((cc * 256 + ku * 16) ^ ((cc & 7) << 4))) = v;
        }
        __syncthreads();  // staged data visible

        // ---- 4 MFMA steps (k=32 each) ----
#pragma unroll
        for (int s = 0; s < 4; ++s) {
            const unsigned int mb =
                *(const unsigned char*)(lds + 32768 + lrow * 20 + s * 4 + g);
            const int t = it * 4 + s;
            const float4 fa = *(const float4*)(lds + 35328 + t * 128 + g * 32);
            const float4 fb = *(const float4*)(lds + 35328 + t * 128 + g * 32 + 16);
            const float ff[8] = {fa.x, fa.y, fa.z, fa.w, fb.x, fb.y, fb.z, fb.w};

            bf16x8 pa;
#pragma unroll
            for (int j = 0; j < 8; ++j) {
                const float x = f1a + ff[j];
                const float e = __builtin_amdgcn_exp2f(fmaxf(x, ALPHA * x));
                pa[j] = (bf16)((mb & (1u << j)) ? e : 0.f);
            }
#pragma unroll
            for (int j = 0; j < 8; ++j) rs0 += (float)pa[j];

            __builtin_amdgcn_s_setprio(1);
#pragma unroll
            for (int nf = 0; nf < 8; ++nf) {
                const int c = nf * 16 + l15;
                const bf16x8 bh = *(const bf16x8*)(
                    lds + ((c * 256 + s * 64 + g * 16) ^ ((c & 7) << 4)));
                acc[nf] = __builtin_amdgcn_mfma_f32_16x16x32_bf16(pa, bh, acc[nf], 0, 0, 0);
            }
            __builtin_amdgcn_s_setprio(0);
        }
    }

    // rowsum partial (combine the 4 g-groups)
    rs0 += __shfl_xor(rs0, 16);
    rs0 += __shfl_xor(rs0, 32);
    if (l < 16) rs_part[(size_t)ks * NN + row0 + lrow] = rs0;

    // ---- epilogue: two halves through accL[64][132], contiguous writes ----
    float* accL = (float*)lds;
#pragma unroll
    for (int half = 0; half < 2; ++half) {
        __syncthreads();
        if ((wv >> 2) == half) {
            const int rbase = (wv & 3) * 16;
#pragma unroll
            for (int nf = 0; nf < 8; ++nf)
#pragma unroll
                for (int r = 0; r < 4; ++r)
                    accL[(rbase + g * 4 + r) * 132 + nf * 16 + l15] = acc[nf][r];
        }
        __syncthreads();
        const int rr = tid >> 3;  // 0..63
        const int seg = tid & 7;  // 16 floats each
        float* dst = O_part + ((size_t)ks << 20) +
                     (size_t)(row0 + half * 64 + rr) * F_OUT + seg * 16;
        const float* src = accL + rr * 132 + seg * 16;
        *(float4*)(dst + 0) = *(const float4*)(src + 0);
        *(float4*)(dst + 4) = *(const float4*)(src + 4);
        *(float4*)(dst + 8) = *(const float4*)(src + 8);
        *(float4*)(dst + 12) = *(const float4*)(src + 12);
    }
}

// ---------------------------------------------------------------------------
// K3: reduce k-slices: out = (sum_s O_part[s]) / (sum_s rs_part[s]).
// ---------------------------------------------------------------------------
__global__ __launch_bounds__(256) void gat_reduce(const float* __restrict__ O_part,
                                                  const float* __restrict__ rs_part,
                                                  float* __restrict__ out) {
    const int idx = blockIdx.x * 256 + threadIdx.x;
    const int r = idx >> 5;
    const int c = (idx & 31) * 4;
    float rsum = 0.f;
#pragma unroll
    for (int s = 0; s < KSLICES; ++s) rsum += rs_part[(size_t)s * NN + r];
    float4 o = {0.f, 0.f, 0.f, 0.f};
#pragma unroll
    for (int s = 0; s < KSLICES; ++s) {
        const float4 v =
            *(const float4*)(O_part + ((size_t)s << 20) + (size_t)r * F_OUT + c);
        o.x += v.x;
        o.y += v.y;
        o.z += v.z;
        o.w += v.w;
    }
    const float inv = 1.0f / rsum;
    o.x *= inv;
    o.y *= inv;
    o.z *= inv;
    o.w *= inv;
    *(float4*)(out + (size_t)r * F_OUT + c) = o;
}

// ---------------------------------------------------------------------------
extern "C" void kernel_launch(void* const* d_in, const int* in_sizes, int n_in,
                              void* d_out, int out_size, void* d_ws, size_t ws_size,
                              hipStream_t stream) {
    const float* h = (const float*)d_in[0];  // (8192, 256) fp32
    const int* adj = (const int*)d_in[1];    // (8192, 8192) int32
    const float* W = (const float*)d_in[2];  // (128, 256) fp32
    const float* a = (const float*)d_in[3];  // (1, 256) fp32
    float* out = (float*)d_out;              // (8192, 128) fp32

    char* ws = (char*)d_ws;
    const size_t MB = 1024 * 1024;
    bf16* WhT = (bf16*)ws;                                 // 2 MB
    float* f1L = (float*)(ws + 2 * MB);                    // 32 KB
    float* f2L = f1L + NN;                                 // 32 KB
    unsigned char* maskP = (unsigned char*)(ws + 3 * MB);  // 8 MB [ks][row][128B]
    float* rs_part = (float*)(ws + 11 * MB);               // 256 KB
    float* O_part = (float*)(ws + 12 * MB);                // 32 MB

    gat_whpack<<<2176, 256, 0, stream>>>(adj, h, W, a, maskP, WhT, f1L, f2L);
    gat_flash6<<<512, 512, 0, stream>>>(maskP, WhT, f1L, f2L, O_part, rs_part);
    gat_reduce<<<NN * F_OUT / 4 / 256, 256, 0, stream>>>(O_part, rs_part, out);
}